// Round 11
// baseline (71.991 us; speedup 1.0000x reference)
//
#include <hip/hip_runtime.h>

#define BATCH 4
#define LQ    10000
#define DM    256
#define NH    8
#define NP    4
#define HWD   100
#define LIN   10000

typedef unsigned short ushort_t;
typedef __attribute__((ext_vector_type(8))) short bf16x8;
typedef __attribute__((ext_vector_type(8))) unsigned short u16x8;
typedef __attribute__((ext_vector_type(4))) float f32x4;

__device__ __forceinline__ unsigned short f2bf(float f) {
    unsigned int u = __float_as_uint(f);
    u += 0x7FFFu + ((u >> 16) & 1u);          // round-to-nearest-even
    return (unsigned short)(u >> 16);
}

__device__ __forceinline__ u16x8 pack8(float4 f0, float4 f1) {
    u16x8 pk;
    pk[0] = f2bf(f0.x); pk[1] = f2bf(f0.y);
    pk[2] = f2bf(f0.z); pk[3] = f2bf(f0.w);
    pk[4] = f2bf(f1.x); pk[5] = f2bf(f1.y);
    pk[6] = f2bf(f1.z); pk[7] = f2bf(f1.w);
    return pk;
}

// async global->LDS, 16B per lane. LDS dest = wave-uniform base + lane*16.
__device__ __forceinline__ void gload16(const ushort_t* g, ushort_t* l) {
    __builtin_amdgcn_global_load_lds(
        (const __attribute__((address_space(1))) void*)g,
        (__attribute__((address_space(3))) void*)l, 16, 0, 0);
}

// counted waits + raw barrier (T3/T4): prefetches stay in flight across the
// barrier instead of being drained by __syncthreads' implicit vmcnt(0).
#define WAIT_VM2()  asm volatile("s_waitcnt vmcnt(2)" ::: "memory")
#define WAIT_VM0()  asm volatile("s_waitcnt vmcnt(0)" ::: "memory")
#define WAIT_LGKM() asm volatile("s_waitcnt lgkmcnt(0)" ::: "memory")
#define BARRIER()   { __builtin_amdgcn_s_barrier(); __builtin_amdgcn_sched_barrier(0); }

// Pre-swizzle (4-chunk, within each 32-k tile): storage chunk
// ct = lc ^ ((n>>1)&3). Frag ds_read_b128 lands conflict-free; staging is a
// LINEAR copy of the pre-swizzled storage -> gload16-compatible.
// ---------------------------------------------------------------------------
// Prep: swizzled WtV/WtO (256x256), Wcomb (96x256) + bcomb. grid (256,3).
// ---------------------------------------------------------------------------
__global__ __launch_bounds__(256) void prep_kernel(
    const float* __restrict__ Wv, const float* __restrict__ Wout,
    const float* __restrict__ Woff, const float* __restrict__ Wa,
    const float* __restrict__ boff, const float* __restrict__ ba,
    ushort_t* __restrict__ WtV, ushort_t* __restrict__ WtO,
    ushort_t* __restrict__ Wcomb, float* __restrict__ bcomb)
{
    const int n = blockIdx.x, k = threadIdx.x;
    const int t32 = k >> 5, lc = (k >> 3) & 3, j = k & 7;
    const int ct = lc ^ ((n >> 1) & 3);
    const size_t addr = (size_t)n * 256 + t32 * 32 + ct * 8 + j;
    if (blockIdx.y == 0) {
        WtV[addr] = f2bf(Wv[(size_t)k * 256 + n]);
    } else if (blockIdx.y == 1) {
        WtO[addr] = f2bf(Wout[(size_t)k * 256 + n]);
    } else if (n < 96) {
        float w = (n < 64) ? Woff[(size_t)k * 64 + n] : Wa[(size_t)k * 32 + (n - 64)];
        Wcomb[addr] = f2bf(w);
        if (k == 0) bcomb[n] = (n < 64) ? boff[n] : ba[n - 64];
    }
}

// ---------------------------------------------------------------------------
// Combined input GEMMs (BM=64, BK=32, 4 waves, dbuf LDS), counted-vmcnt
// pipeline: B(t+1) gload16 + A(t+2) reg-loads in flight across raw barriers.
//   bid <  625 : value_hm[((b*8+h)*LIN+pix)*32+ch] = bf16(flat @ Wv + bv)
//   bid >= 625 : oaproj[M][96] = f32(query @ [Woff|Wa]^T + bcomb)
// ---------------------------------------------------------------------------
__global__ __launch_bounds__(256) void gemm_in_kernel(
    const float* __restrict__ flat, const float* __restrict__ query,
    const ushort_t* __restrict__ WtV, const ushort_t* __restrict__ Wcomb,
    const float* __restrict__ bv, const float* __restrict__ bcomb,
    ushort_t* __restrict__ value, float* __restrict__ oaproj)
{
    __shared__ ushort_t As[2][64 * 32];     // 2 x 4 KB
    __shared__ ushort_t Bs[2][256 * 32];    // 2 x 16 KB

    const int tid  = threadIdx.x;
    const int lane = tid & 63;
    const int wv   = tid >> 6;

    const int ar  = tid >> 2;               // A staging row 0..63
    const int akb = tid & 3;                // A staging chunk 0..3
    const int asw = (akb ^ ((ar >> 1) & 3)) * 8;
    const int fr = lane & 15, kb = lane >> 4;
    const int ln4 = lane >> 2, lc4 = lane & 3;   // gload16 decomposition

    if (blockIdx.x < 625) {
        // ---------------- value GEMM ----------------
        const int row0 = blockIdx.x * 64;
        const float* ap = &flat[(size_t)(row0 + ar) * 256 + akb * 8];
        const f32x4 zero = {0.f, 0.f, 0.f, 0.f};
        f32x4 acc[4][4];
        #pragma unroll
        for (int m = 0; m < 4; ++m)
            #pragma unroll
            for (int n = 0; n < 4; ++n) acc[m][n] = zero;

        float4 an0[2], an1[2];              // 2-deep A prefetch slots

        // prologue: A(0) regs -> As[0]; B(0) gload16; A(1) -> slot 1
        {
            float4 f0 = *reinterpret_cast<const float4*>(ap);
            float4 f1 = *reinterpret_cast<const float4*>(ap + 4);
            #pragma unroll
            for (int it = 0; it < 4; ++it) {
                int r0 = (it * 4 + wv) * 16;
                gload16(&WtV[(size_t)(r0 + ln4) * 256 + lc4 * 8], &Bs[0][r0 * 32]);
            }
            *reinterpret_cast<u16x8*>(&As[0][ar * 32 + asw]) = pack8(f0, f1);
            an0[1] = *reinterpret_cast<const float4*>(ap + 32);
            an1[1] = *reinterpret_cast<const float4*>(ap + 36);
        }
        WAIT_VM2(); WAIT_LGKM(); BARRIER();

        #pragma unroll
        for (int t = 0; t < 8; ++t) {
            const int c = t & 1;
            if (t + 1 < 8) {
                #pragma unroll
                for (int it = 0; it < 4; ++it) {
                    int r0 = (it * 4 + wv) * 16;
                    gload16(&WtV[(size_t)(r0 + ln4) * 256 + (t + 1) * 32 + lc4 * 8],
                            &Bs[c ^ 1][r0 * 32]);
                }
            }
            if (t + 2 < 8) {
                an0[c] = *reinterpret_cast<const float4*>(ap + (t + 2) * 32);
                an1[c] = *reinterpret_cast<const float4*>(ap + (t + 2) * 32 + 4);
            }
            if (t + 1 < 8)
                *reinterpret_cast<u16x8*>(&As[c ^ 1][ar * 32 + asw]) =
                    pack8(an0[c ^ 1], an1[c ^ 1]);

            bf16x8 af[4], bf[4];
            #pragma unroll
            for (int m = 0; m < 4; ++m) {
                int r = m * 16 + fr;
                af[m] = *reinterpret_cast<const bf16x8*>(
                    &As[c][r * 32 + ((kb ^ ((r >> 1) & 3)) * 8)]);
            }
            #pragma unroll
            for (int n = 0; n < 4; ++n) {
                int cc = wv * 64 + n * 16 + fr;
                bf[n] = *reinterpret_cast<const bf16x8*>(
                    &Bs[c][cc * 32 + ((kb ^ ((cc >> 1) & 3)) * 8)]);
            }
            #pragma unroll
            for (int m = 0; m < 4; ++m)
                #pragma unroll
                for (int n = 0; n < 4; ++n)
                    acc[m][n] = __builtin_amdgcn_mfma_f32_16x16x32_bf16(
                        af[m], bf[n], acc[m][n], 0, 0, 0);

            if (t < 6) { WAIT_VM2(); } else { WAIT_VM0(); }
            WAIT_LGKM(); BARRIER();
        }

        // epilogue -> head-major value layout
        #pragma unroll
        for (int n = 0; n < 4; ++n) {
            int cc = wv * 64 + n * 16 + fr;
            float bb = bv[cc];
            int hh = cc >> 5, ch = cc & 31;
            #pragma unroll
            for (int m = 0; m < 4; ++m) {
                #pragma unroll
                for (int j = 0; j < 4; ++j) {
                    int r = row0 + m * 16 + kb * 4 + j;
                    int rb = (int)((unsigned)r / 10000u);
                    int pix = r - rb * 10000;
                    size_t addr = (((size_t)(rb * 8 + hh)) * LIN + pix) * 32 + ch;
                    value[addr] = f2bf(acc[m][n][j] + bb);
                }
            }
        }
    } else {
        // ---------------- projection GEMM ----------------
        const int row0 = (blockIdx.x - 625) * 64;
        const float* ap = &query[(size_t)(row0 + ar) * 256 + akb * 8];
        const f32x4 zero = {0.f, 0.f, 0.f, 0.f};
        f32x4 acc[6];
        #pragma unroll
        for (int n = 0; n < 6; ++n) acc[n] = zero;

        float4 an0[2], an1[2];

        {
            float4 f0 = *reinterpret_cast<const float4*>(ap);
            float4 f1 = *reinterpret_cast<const float4*>(ap + 4);
            #pragma unroll
            for (int it = 0; it < 2; ++it) {
                int r0 = (it * 4 + wv) * 16;
                if (r0 < 96)
                    gload16(&Wcomb[(size_t)(r0 + ln4) * 256 + lc4 * 8], &Bs[0][r0 * 32]);
            }
            *reinterpret_cast<u16x8*>(&As[0][ar * 32 + asw]) = pack8(f0, f1);
            an0[1] = *reinterpret_cast<const float4*>(ap + 32);
            an1[1] = *reinterpret_cast<const float4*>(ap + 36);
        }
        WAIT_VM2(); WAIT_LGKM(); BARRIER();

        #pragma unroll
        for (int t = 0; t < 8; ++t) {
            const int c = t & 1;
            if (t + 1 < 8) {
                #pragma unroll
                for (int it = 0; it < 2; ++it) {
                    int r0 = (it * 4 + wv) * 16;
                    if (r0 < 96)
                        gload16(&Wcomb[(size_t)(r0 + ln4) * 256 + (t + 1) * 32 + lc4 * 8],
                                &Bs[c ^ 1][r0 * 32]);
                }
            }
            if (t + 2 < 8) {
                an0[c] = *reinterpret_cast<const float4*>(ap + (t + 2) * 32);
                an1[c] = *reinterpret_cast<const float4*>(ap + (t + 2) * 32 + 4);
            }
            if (t + 1 < 8)
                *reinterpret_cast<u16x8*>(&As[c ^ 1][ar * 32 + asw]) =
                    pack8(an0[c ^ 1], an1[c ^ 1]);

            bf16x8 af;
            {
                int r = wv * 16 + fr;
                af = *reinterpret_cast<const bf16x8*>(
                    &As[c][r * 32 + ((kb ^ ((r >> 1) & 3)) * 8)]);
            }
            #pragma unroll
            for (int n = 0; n < 6; ++n) {
                int cc = n * 16 + fr;
                bf16x8 bf = *reinterpret_cast<const bf16x8*>(
                    &Bs[c][cc * 32 + ((kb ^ ((cc >> 1) & 3)) * 8)]);
                acc[n] = __builtin_amdgcn_mfma_f32_16x16x32_bf16(
                    af, bf, acc[n], 0, 0, 0);
            }

            if (t < 6) { WAIT_VM2(); } else { WAIT_VM0(); }
            WAIT_LGKM(); BARRIER();
        }

        #pragma unroll
        for (int n = 0; n < 6; ++n) {
            int cc = n * 16 + fr;
            float bb = bcomb[cc];
            #pragma unroll
            for (int j = 0; j < 4; ++j) {
                int r = row0 + wv * 16 + kb * 4 + j;
                oaproj[(size_t)r * 96 + cc] = acc[n][j] + bb;
            }
        }
    }
}

// ---------------------------------------------------------------------------
// Deform (R8/R9 structure, L2-resident per-map gather). ws2 store uses the
// 4-chunk pre-swizzle so gemm_out can stage it with gload16.
// ---------------------------------------------------------------------------
__global__ __launch_bounds__(256, 4) void deform_kernel(
    const float* __restrict__ oaproj, const float* __restrict__ refpts,
    const ushort_t* __restrict__ value, ushort_t* __restrict__ out)
{
    __shared__ int4   soff[NP * 64];
    __shared__ float4 swt [NP * 64];

    const int blk = blockIdx.x;
    const int xcd = blk & 7;
    const int sub = (blk >> 3) & 3;
    const int chunk = blk >> 5;
    const int map = xcd * 4 + sub;
    const int b = map >> 3, h = map & 7;
    const int q0 = chunk * 64;

    const int tid = threadIdx.x;

    if (tid < 64) {
        const int qg = q0 + tid;
        if (qg >= LQ) {
            int4 zi = {0, 0, 0, 0};
            float4 zf = {0.f, 0.f, 0.f, 0.f};
            #pragma unroll
            for (int p = 0; p < NP; ++p) { soff[p * 64 + tid] = zi; swt[p * 64 + tid] = zf; }
        } else {
            const size_t row = (size_t)b * LQ + qg;
            const float* oa = oaproj + row * 96;
            float4 l4 = *reinterpret_cast<const float4*>(oa + 64 + h * 4);
            float mx = fmaxf(fmaxf(l4.x, l4.y), fmaxf(l4.z, l4.w));
            float e0 = __expf(l4.x - mx), e1 = __expf(l4.y - mx);
            float e2 = __expf(l4.z - mx), e3 = __expf(l4.w - mx);
            float inv = 1.f / (e0 + e1 + e2 + e3);
            float ew[4] = {e0 * inv, e1 * inv, e2 * inv, e3 * inv};
            float4 o0 = *reinterpret_cast<const float4*>(oa + h * 8);
            float4 o1 = *reinterpret_cast<const float4*>(oa + h * 8 + 4);
            float oxv[4] = {o0.x, o0.z, o1.x, o1.z};
            float oyv[4] = {o0.y, o0.w, o1.y, o1.w};
            const float* rp = refpts + row * 4;
            float cx = rp[0], cy = rp[1], rw = rp[2], rh = rp[3];
            #pragma unroll
            for (int p = 0; p < NP; ++p) {
                float x = (cx + oxv[p] * rw * 0.125f) * (float)HWD - 0.5f;
                float y = (cy + oyv[p] * rh * 0.125f) * (float)HWD - 0.5f;
                float x0f = floorf(x), y0f = floorf(y);
                float wx = x - x0f, wy = y - y0f;
                int x0 = (int)x0f, y0 = (int)y0f;
                int x1 = x0 + 1, y1 = y0 + 1;
                float vx0 = (x0 >= 0 && x0 < HWD) ? 1.f : 0.f;
                float vx1 = (x1 >= 0 && x1 < HWD) ? 1.f : 0.f;
                float vy0 = (y0 >= 0 && y0 < HWD) ? 1.f : 0.f;
                float vy1 = (y1 >= 0 && y1 < HWD) ? 1.f : 0.f;
                int cx0 = min(max(x0, 0), HWD - 1), cx1 = min(max(x1, 0), HWD - 1);
                int cy0 = min(max(y0, 0), HWD - 1), cy1 = min(max(y1, 0), HWD - 1);
                float aw = ew[p];
                int4 of = {cy0 * HWD + cx0, cy0 * HWD + cx1,
                           cy1 * HWD + cx0, cy1 * HWD + cx1};
                float4 wt = {aw * (1.f - wx) * (1.f - wy) * vx0 * vy0,
                             aw * wx * (1.f - wy) * vx1 * vy0,
                             aw * (1.f - wx) * wy * vx0 * vy1,
                             aw * wx * wy * vx1 * vy1};
                soff[p * 64 + tid] = of;
                swt [p * 64 + tid] = wt;
            }
        }
    }
    __syncthreads();

    const int q = tid >> 2, c8 = tid & 3;
    const int qg = q0 + q;
    const ushort_t* vb = value + (size_t)map * (LIN * 32) + c8 * 8;

    int4 of[4]; float4 w4[4];
    #pragma unroll
    for (int p = 0; p < NP; ++p) {
        of[p] = soff[p * 64 + q];
        w4[p] = swt [p * 64 + q];
    }
    uint4 vv[4][4];
    #pragma unroll
    for (int p = 0; p < NP; ++p) {
        vv[p][0] = *reinterpret_cast<const uint4*>(vb + ((size_t)of[p].x << 5));
        vv[p][1] = *reinterpret_cast<const uint4*>(vb + ((size_t)of[p].y << 5));
        vv[p][2] = *reinterpret_cast<const uint4*>(vb + ((size_t)of[p].z << 5));
        vv[p][3] = *reinterpret_cast<const uint4*>(vb + ((size_t)of[p].w << 5));
    }
    float a0 = 0.f, a1 = 0.f, a2 = 0.f, a3 = 0.f;
    float a4 = 0.f, a5 = 0.f, a6 = 0.f, a7 = 0.f;
    #define ACC(V, W) { const float w_ = (W); const uint4 v_ = (V); \
        a0 += w_ * __uint_as_float(v_.x << 16); \
        a1 += w_ * __uint_as_float(v_.x & 0xffff0000u); \
        a2 += w_ * __uint_as_float(v_.y << 16); \
        a3 += w_ * __uint_as_float(v_.y & 0xffff0000u); \
        a4 += w_ * __uint_as_float(v_.z << 16); \
        a5 += w_ * __uint_as_float(v_.z & 0xffff0000u); \
        a6 += w_ * __uint_as_float(v_.w << 16); \
        a7 += w_ * __uint_as_float(v_.w & 0xffff0000u); }
    #pragma unroll
    for (int p = 0; p < NP; ++p) {
        ACC(vv[p][0], w4[p].x);
        ACC(vv[p][1], w4[p].y);
        ACC(vv[p][2], w4[p].z);
        ACC(vv[p][3], w4[p].w);
    }
    #undef ACC

    if (qg < LQ) {
        const size_t orow = (size_t)b * LQ + qg;
        u16x8 pk;
        pk[0] = f2bf(a0); pk[1] = f2bf(a1);
        pk[2] = f2bf(a2); pk[3] = f2bf(a3);
        pk[4] = f2bf(a4); pk[5] = f2bf(a5);
        pk[6] = f2bf(a6); pk[7] = f2bf(a7);
        // 4-chunk pre-swizzled store: cc = h*4+c8 -> tile t32 = cc>>2,
        // storage ct = (cc&3) ^ ((orow>>1)&3)
        const int cc = h * 4 + c8;
        const int t32 = cc >> 2;
        const int ct = (cc & 3) ^ ((int)(orow >> 1) & 3);
        *reinterpret_cast<u16x8*>(&out[orow * 256 + t32 * 32 + ct * 8]) = pk;
    }
}

// ---------------------------------------------------------------------------
// Output GEMM: out = ws2 @ Wout + bout (f32). BM=64, BK=32, 2-phase dbuf,
// both A (pre-swizzled ws2) and B (pre-swizzled WtO) staged via gload16.
// ---------------------------------------------------------------------------
__global__ __launch_bounds__(256) void gemm_out_kernel(
    const ushort_t* __restrict__ A, const ushort_t* __restrict__ Wt,
    const float* __restrict__ bias, float* __restrict__ Cout)
{
    __shared__ ushort_t As[2][64 * 32];
    __shared__ ushort_t Bs[2][256 * 32];

    const int tid  = threadIdx.x;
    const int lane = tid & 63;
    const int wv   = tid >> 6;
    const int row0 = blockIdx.x * 64;

    const f32x4 zero = {0.f, 0.f, 0.f, 0.f};
    f32x4 acc[4][4];
    #pragma unroll
    for (int m = 0; m < 4; ++m)
        #pragma unroll
        for (int n = 0; n < 4; ++n) acc[m][n] = zero;

    const int fr = lane & 15, kb = lane >> 4;
    const int ln4 = lane >> 2, lc4 = lane & 3;

    // prologue: stage tile 0
    {
        gload16(&A[(size_t)(row0 + wv * 16 + ln4) * 256 + lc4 * 8],
                &As[0][wv * 512]);
        #pragma unroll
        for (int it = 0; it < 4; ++it) {
            int r0 = (it * 4 + wv) * 16;
            gload16(&Wt[(size_t)(r0 + ln4) * 256 + lc4 * 8], &Bs[0][r0 * 32]);
        }
    }
    __syncthreads();

    int c = 0;
    for (int t = 0; t < 8; ++t) {
        const int kn = (t + 1) * 32;
        if (t < 7) {
            gload16(&A[(size_t)(row0 + wv * 16 + ln4) * 256 + kn + lc4 * 8],
                    &As[c ^ 1][wv * 512]);
            #pragma unroll
            for (int it = 0; it < 4; ++it) {
                int r0 = (it * 4 + wv) * 16;
                gload16(&Wt[(size_t)(r0 + ln4) * 256 + kn + lc4 * 8],
                        &Bs[c ^ 1][r0 * 32]);
            }
        }
        bf16x8 af[4], bf[4];
        #pragma unroll
        for (int m = 0; m < 4; ++m) {
            int r = m * 16 + fr;
            af[m] = *reinterpret_cast<const bf16x8*>(
                &As[c][r * 32 + ((kb ^ ((r >> 1) & 3)) * 8)]);
        }
        #pragma unroll
        for (int n = 0; n < 4; ++n) {
            int cc = wv * 64 + n * 16 + fr;
            bf[n] = *reinterpret_cast<const bf16x8*>(
                &Bs[c][cc * 32 + ((kb ^ ((cc >> 1) & 3)) * 8)]);
        }
        #pragma unroll
        for (int m = 0; m < 4; ++m)
            #pragma unroll
            for (int n = 0; n < 4; ++n)
                acc[m][n] = __builtin_amdgcn_mfma_f32_16x16x32_bf16(
                    af[m], bf[n], acc[m][n], 0, 0, 0);
        __syncthreads();
        c ^= 1;
    }

    #pragma unroll
    for (int m = 0; m < 4; ++m) {
        #pragma unroll
        for (int n = 0; n < 4; ++n) {
            int cc = wv * 64 + n * 16 + fr;
            float bb = bias[cc];
            #pragma unroll
            for (int j = 0; j < 4; ++j) {
                int r = row0 + m * 16 + kb * 4 + j;
                Cout[(size_t)r * 256 + cc] = acc[m][n][j] + bb;
            }
        }
    }
}

// ---------------------------------------------------------------------------
extern "C" void kernel_launch(void* const* d_in, const int* in_sizes, int n_in,
                              void* d_out, int out_size, void* d_ws, size_t ws_size,
                              hipStream_t stream)
{
    const float* query  = (const float*)d_in[0];
    const float* refpts = (const float*)d_in[1];
    const float* flat   = (const float*)d_in[2];
    const float* Wv   = (const float*)d_in[6];
    const float* bv   = (const float*)d_in[7];
    const float* Woff = (const float*)d_in[8];
    const float* boff = (const float*)d_in[9];
    const float* Wa   = (const float*)d_in[10];
    const float* ba   = (const float*)d_in[11];
    const float* Wout = (const float*)d_in[12];
    const float* bout = (const float*)d_in[13];
    float* out = (float*)d_out;

    const size_t MROWS = (size_t)BATCH * LIN;            // 40000
    ushort_t* value  = (ushort_t*)d_ws;                  // [b][h][pix][32] bf16
    ushort_t* ws2    = value + MROWS * DM;               // 40000x256 bf16 (pre-swizzled)
    ushort_t* WtV    = ws2 + MROWS * DM;                 // 256x256 bf16 (pre-swizzled)
    ushort_t* WtO    = WtV + 256 * 256;                  // 256x256 bf16 (pre-swizzled)
    ushort_t* Wcomb  = WtO + 256 * 256;                  // 96x256 bf16 (pre-swizzled)
    float*    bcomb  = (float*)(Wcomb + 96 * 256);       // 96 f32 (+pad)
    float*    oaproj = bcomb + 128;                      // 40000x96 f32

    dim3 blk(256);

    prep_kernel<<<dim3(256, 3), blk, 0, stream>>>(
        Wv, Wout, Woff, Wa, boff, ba, WtV, WtO, Wcomb, bcomb);

    gemm_in_kernel<<<dim3(1250), blk, 0, stream>>>(
        flat, query, WtV, Wcomb, bv, bcomb, value, oaproj);

    deform_kernel<<<dim3(157 * 32), blk, 0, stream>>>(
        oaproj, refpts, value, ws2);

    gemm_out_kernel<<<dim3(MROWS / 64), blk, 0, stream>>>(
        ws2, WtO, bout, out);
}